// Round 4
// baseline (5951.316 us; speedup 1.0000x reference)
//
#include <hip/hip_runtime.h>
#include <hip/hip_bf16.h>
#include <cmath>

#define NDIM 64
#define P    68          // LDS row stride (floats); rows 16B-aligned
#define NDEG 18          // Chebyshev degree for log on [0.9, 8.0]; trunc err ~4e-7
#define TRI  2080        // 64*65/2

struct Coeffs {
    float c[NDEG + 1];
    float m_over_h;      // m/h where X~ = (X - m I)/h
    float inv_h;
};

// SPD => symmetric under the TRUE dtype; wrong reinterpretation gives O(1)/NaN residual.
__device__ __forceinline__ bool sniff_is_bf16(const void* xin)
{
    const float*          f0 = (const float*)xin;
    const unsigned short* h0 = (const unsigned short*)xin;
    const int pi[8] = {1, 3, 5, 2, 4, 6, 7, 8};
    const int pj[8] = {2, 7, 11, 9, 13, 17, 23, 31};
    float fsym = 0.f, bsym = 0.f;
    #pragma unroll
    for (int p = 0; p < 8; ++p) {
        const int i = pi[p], j = pj[p];
        fsym += fabsf(f0[i * NDIM + j] - f0[j * NDIM + i]);
        union { unsigned u; float f; } ua, ub;
        ua.u = ((unsigned)h0[i * NDIM + j]) << 16;
        ub.u = ((unsigned)h0[j * NDIM + i]) << 16;
        bsym += fabsf(ua.f - ub.f);
    }
    if (fsym != fsym) return true;    // fp32 view NaN -> data is bf16
    if (bsym != bsym) return false;   // bf16 view NaN -> data is fp32
    return bsym < fsym;
}

// One wave per matrix; thread t owns row t. Output: FP32, row-major triu (np.triu_indices order).
__global__ __launch_bounds__(64)
void spd_log_row(const void* __restrict__ xin,
                 float* __restrict__ out,
                 Coeffs co)
{
    __shared__ __align__(16) float Xs[NDIM * P];
    __shared__ __align__(16) float Ta[NDIM * P];
    __shared__ __align__(16) float Tb[NDIM * P];

    const int b = blockIdx.x;
    const int t = threadIdx.x;      // owned row, 0..63

    const bool isb = sniff_is_bf16(xin);

    // ---------- load + spectral shift: X~ = (X - m I)/h ----------
    const float inv_h = co.inv_h, moh = co.m_over_h;
    if (isb) {
        const unsigned short* xh = (const unsigned short*)xin + (size_t)b * (NDIM * NDIM);
        for (int e = t; e < NDIM * NDIM; e += 64) {
            union { unsigned u; float f; } uv;
            uv.u = ((unsigned)xh[e]) << 16;
            const int i = e >> 6, j = e & 63;
            float v = uv.f * inv_h;
            if (i == j) v -= moh;
            Xs[i * P + j] = v;
            Tb[i * P + j] = v;                       // T_1 = X~
            Ta[i * P + j] = (i == j) ? 1.f : 0.f;    // T_0 = I
        }
    } else {
        const float* xf = (const float*)xin + (size_t)b * (NDIM * NDIM);
        for (int e = t; e < NDIM * NDIM; e += 64) {
            const int i = e >> 6, j = e & 63;
            float v = xf[e] * inv_h;
            if (i == j) v -= moh;
            Xs[i * P + j] = v;
            Tb[i * P + j] = v;
            Ta[i * P + j] = (i == j) ? 1.f : 0.f;
        }
    }
    __syncthreads();

    // ---------- y = c0 I + c1 X~   (row t) ----------
    float y[NDIM];
    #pragma unroll
    for (int j = 0; j < NDIM; ++j)
        y[j] = co.c[1] * Xs[t * P + j] + ((t == j) ? co.c[0] : 0.f);

    float* Tc = Tb;   // T_{k-1}
    float* Tp = Ta;   // T_{k-2}, overwritten in place with T_k (row-exclusive)

    for (int k = 2; k <= NDEG; ++k) {
        float acc[NDIM];
        #pragma unroll
        for (int j = 0; j < NDIM; ++j) acc[j] = 0.f;

        #pragma unroll 4
        for (int kk = 0; kk < NDIM; ++kk) {
            const float xr = Xs[t * P + kk];
            const float* tr = &Tc[kk * P];          // wave-uniform row -> broadcast reads
            #pragma unroll
            for (int j = 0; j < NDIM; ++j)
                acc[j] = fmaf(xr, tr[j], acc[j]);
        }

        // T_k = 2 X~ Tc - Tp ; accumulate into y; rotate in place (row-exclusive).
        const float ck = co.c[k];
        #pragma unroll
        for (int j = 0; j < NDIM; ++j) {
            const float tkj = 2.f * acc[j] - Tp[t * P + j];
            y[j] += ck * tkj;
            Tp[t * P + j] = tkj;
        }
        float* tmp = Tc; Tc = Tp; Tp = tmp;
        __syncthreads();
    }

    // ---------- FP32 output: row-major upper-tri incl. diagonal (np.triu_indices order) ----------
    const size_t ob   = (size_t)b * TRI;
    const int row_off = t * NDIM - (t * (t - 1)) / 2;   // start of row t in triu flatten
    for (int j = t; j < NDIM; ++j)
        out[ob + row_off + (j - t)] = y[j];
}

extern "C" void kernel_launch(void* const* d_in, const int* in_sizes, int n_in,
                              void* d_out, int out_size, void* d_ws, size_t ws_size,
                              hipStream_t stream)
{
    (void)n_in; (void)d_ws; (void)ws_size; (void)out_size;

    // Chebyshev coefficients of log on [a,b]:
    // log(m + h t) = log(h/(2g)) + sum_{k>=1} 2(-1)^{k+1} g^k / k * T_k(t),
    // g = (1 - sqrt(1 - (h/m)^2)) / (h/m).  Verified at t = -1, 0, +1.
    const double a = 0.90, bnd = 8.00;
    const double m = 0.5 * (a + bnd), h = 0.5 * (bnd - a);
    const double alpha = h / m;
    const double gam = (1.0 - sqrt(1.0 - alpha * alpha)) / alpha;

    Coeffs co;
    co.c[0] = (float)log(h / (2.0 * gam));
    double g = 1.0;
    for (int k = 1; k <= NDEG; ++k) {
        g *= gam;
        co.c[k] = (float)((((k & 1) ? 2.0 : -2.0) * g) / (double)k);
    }
    co.m_over_h = (float)(m / h);
    co.inv_h    = (float)(1.0 / h);

    const int B = in_sizes[0] / (NDIM * NDIM);
    spd_log_row<<<B, 64, 0, stream>>>(d_in[0], (float*)d_out, co);
}

// Round 5
// 280.715 us; speedup vs baseline: 21.2006x; 21.2006x over previous
//
#include <hip/hip_runtime.h>
#include <hip/hip_bf16.h>
#include <cmath>

#define NDIM  64
#define PSTR  72        // LDS plane row stride in f16 (144 B, 16B-aligned rows)
#define NDEG  19        // Chebyshev degree for log on [0.75, 8.75]; trunc err ~1.3e-6
#define TRI   2080      // 64*65/2
#define MOH   1.1875f   // m/h = 4.75/4
#define TWO_MOH 2.375f  // 2m/h

struct Coeffs {
    float c[NDEG + 1];
};

typedef _Float16 f16x8 __attribute__((ext_vector_type(8)));
typedef _Float16 f16x4 __attribute__((ext_vector_type(4)));
typedef float    f32x4 __attribute__((ext_vector_type(4)));

// SPD => symmetric under the TRUE dtype; wrong reinterpretation gives O(1)/NaN residual.
__device__ __forceinline__ bool sniff_is_bf16(const void* xin)
{
    const float*          f0 = (const float*)xin;
    const unsigned short* h0 = (const unsigned short*)xin;
    const int pi[8] = {1, 3, 5, 2, 4, 6, 7, 8};
    const int pj[8] = {2, 7, 11, 9, 13, 17, 23, 31};
    float fsym = 0.f, bsym = 0.f;
    #pragma unroll
    for (int p = 0; p < 8; ++p) {
        const int i = pi[p], j = pj[p];
        fsym += fabsf(f0[i * NDIM + j] - f0[j * NDIM + i]);
        union { unsigned u; float f; } ua, ub;
        ua.u = ((unsigned)h0[i * NDIM + j]) << 16;
        ub.u = ((unsigned)h0[j * NDIM + i]) << 16;
        bsym += fabsf(ua.f - ub.f);
    }
    if (fsym != fsym) return true;
    if (bsym != bsym) return false;
    return bsym < fsym;
}

// One 64x64 matrix per 256-thread block (4 waves). Wave w owns the 32x32
// output quadrant (m_base = (w&1)*32, n_base = (w>>1)*32), tiled as 2x2
// mfma_f32_16x16x32_f16 tiles. T_k lives in f32 registers (C-layout) AND in
// an f16 LDS plane (B-operand layout; T symmetric so plane[n][k] = T[k][n]).
// Recurrence: T_{k+1} = 2*(X/4)*T_k - (2m/h)*T_k - T_{k-1}; A = f16(X/4) is
// EXACT for bf16 input (exponent shift). One barrier per step, 2 planes.
__global__ __launch_bounds__(256, 4)
void spd_log_mfma(const void* __restrict__ xin,
                  float* __restrict__ out,
                  Coeffs co)
{
    __shared__ __align__(16) _Float16 planes[2][NDIM * PSTR];   // 2 x 9216 B

    const int b    = blockIdx.x;
    const int tid  = threadIdx.x;
    const int wave = tid >> 6;
    const int lane = tid & 63;
    const int l    = lane & 15;     // fragment col (n) / A row (m) index
    const int q    = lane >> 4;     // quad
    const int m_base = (wave & 1) * 32;
    const int n_base = (wave >> 1) * 32;

    const bool isb = sniff_is_bf16(xin);

    // ---------------- stage f16(X/4) into planes[0], row-major ----------------
    if (isb) {
        const unsigned short* xh = (const unsigned short*)xin + (size_t)b * (NDIM * NDIM);
        const uint2* xv = (const uint2*)xh;        // 4 bf16 per uint2
        #pragma unroll
        for (int r = 0; r < 4; ++r) {
            const int e4 = tid + r * 256;          // 1024 quads
            const int e0 = e4 * 4;
            const int row = e0 >> 6, col = e0 & 63;
            const uint2 w = xv[e4];
            union { unsigned u; float f; } c0, c1, c2, c3;
            c0.u = (w.x & 0xffffu) << 16; c1.u = (w.x & 0xffff0000u);
            c2.u = (w.y & 0xffffu) << 16; c3.u = (w.y & 0xffff0000u);
            f16x4 h;
            h[0] = (_Float16)(c0.f * 0.25f); h[1] = (_Float16)(c1.f * 0.25f);
            h[2] = (_Float16)(c2.f * 0.25f); h[3] = (_Float16)(c3.f * 0.25f);
            *(f16x4*)&planes[0][row * PSTR + col] = h;
        }
    } else {
        const float* xf = (const float*)xin + (size_t)b * (NDIM * NDIM);
        const float4* xv = (const float4*)xf;
        #pragma unroll
        for (int r = 0; r < 4; ++r) {
            const int e4 = tid + r * 256;
            const int e0 = e4 * 4;
            const int row = e0 >> 6, col = e0 & 63;
            const float4 w = xv[e4];
            f16x4 h;
            h[0] = (_Float16)(w.x * 0.25f); h[1] = (_Float16)(w.y * 0.25f);
            h[2] = (_Float16)(w.z * 0.25f); h[3] = (_Float16)(w.w * 0.25f);
            *(f16x4*)&planes[0][row * PSTR + col] = h;
        }
    }
    __syncthreads();

    // ---------------- A-fragments: A[m][k] = (X/4)[m][k], fixed all steps ----------------
    // lane holds A[m_base+mt*16+l][kt*32 + q*8 + i], i=0..7  (16B-aligned b128 reads)
    f16x8 afrag[2][2];
    #pragma unroll
    for (int mt = 0; mt < 2; ++mt)
        #pragma unroll
        for (int kt = 0; kt < 2; ++kt)
            afrag[mt][kt] = *(const f16x8*)&planes[0][(m_base + mt * 16 + l) * PSTR + kt * 32 + q * 8];

    // ---------------- init register state in C/D layout ----------------
    // C/D: n = n_base+nt*16+l, m = m_base+mt*16+q*4+r   (m89-verified mapping)
    float tcur[2][2][4], tprev[2][2][4], y[2][2][4];
    #pragma unroll
    for (int mt = 0; mt < 2; ++mt) {
        const int mrow0 = m_base + mt * 16 + q * 4;
        #pragma unroll
        for (int nt = 0; nt < 2; ++nt) {
            const int ncol = n_base + nt * 16 + l;
            const f16x4 tv = *(const f16x4*)&planes[0][ncol * PSTR + mrow0]; // X symmetric
            #pragma unroll
            for (int r = 0; r < 4; ++r) {
                const bool diag = (mrow0 + r) == ncol;
                const float t1 = (float)tv[r] - (diag ? MOH : 0.f);   // T1 = X/4 - (m/h)I
                tcur[mt][nt][r]  = t1;
                tprev[mt][nt][r] = diag ? 1.f : 0.f;                  // T0 = I
                y[mt][nt][r]     = co.c[1] * t1 + (diag ? co.c[0] : 0.f);
            }
        }
    }
    __syncthreads();   // all frag/tcur reads of plane0 done before diag fix

    // plane0 must hold T1 (adjust diagonal); threads 0..63 own one diag elem each
    if (tid < NDIM) {
        const int d = tid * PSTR + tid;
        planes[0][d] = (_Float16)((float)planes[0][d] - MOH);
    }
    __syncthreads();

    // ---------------- Chebyshev recurrence ----------------
    int cur = 0;
    for (int k = 2; k <= NDEG; ++k) {
        // B-fragments of T_{k-1}: B[kk][n] = T[kk][n] = plane[n][kk] (T symmetric)
        f16x8 bfrag[2][2];
        #pragma unroll
        for (int nt = 0; nt < 2; ++nt)
            #pragma unroll
            for (int kt = 0; kt < 2; ++kt)
                bfrag[nt][kt] = *(const f16x8*)&planes[cur][(n_base + nt * 16 + l) * PSTR + kt * 32 + q * 8];

        const float ck = co.c[k];
        #pragma unroll
        for (int mt = 0; mt < 2; ++mt) {
            const int mrow0 = m_base + mt * 16 + q * 4;
            #pragma unroll
            for (int nt = 0; nt < 2; ++nt) {
                const int ncol = n_base + nt * 16 + l;
                f32x4 acc = {0.f, 0.f, 0.f, 0.f};
                acc = __builtin_amdgcn_mfma_f32_16x16x32_f16(afrag[mt][0], bfrag[nt][0], acc, 0, 0, 0);
                acc = __builtin_amdgcn_mfma_f32_16x16x32_f16(afrag[mt][1], bfrag[nt][1], acc, 0, 0, 0);
                f16x4 w;
                #pragma unroll
                for (int r = 0; r < 4; ++r) {
                    // T_k = 2*(X/4)T_{k-1} - (2m/h)T_{k-1} - T_{k-2}
                    const float tn = 2.f * acc[r] - TWO_MOH * tcur[mt][nt][r] - tprev[mt][nt][r];
                    y[mt][nt][r]    += ck * tn;
                    tprev[mt][nt][r] = tcur[mt][nt][r];
                    tcur[mt][nt][r]  = tn;
                    w[r] = (_Float16)tn;
                }
                // transpose-write into next plane: plane[n][m..m+3]
                *(f16x4*)&planes[cur ^ 1][ncol * PSTR + mrow0] = w;
            }
        }
        __syncthreads();
        cur ^= 1;
    }

    // ---------------- output: stage triu in LDS, then coalesced fp32 stores ----------------
    float* ybuf = (float*)&planes[0][0];    // 8320 B <= 18432 B, 16B-aligned
    #pragma unroll
    for (int mt = 0; mt < 2; ++mt) {
        const int mrow0 = m_base + mt * 16 + q * 4;
        #pragma unroll
        for (int nt = 0; nt < 2; ++nt) {
            const int ncol = n_base + nt * 16 + l;
            #pragma unroll
            for (int r = 0; r < 4; ++r) {
                const int m = mrow0 + r;
                if (m <= ncol)
                    ybuf[m * NDIM - (m * (m - 1)) / 2 + (ncol - m)] = y[mt][nt][r];
            }
        }
    }
    __syncthreads();

    float4* dst = (float4*)(out + (size_t)b * TRI);
    const float4* src = (const float4*)ybuf;
    for (int e = tid; e < TRI / 4; e += 256)
        dst[e] = src[e];
}

extern "C" void kernel_launch(void* const* d_in, const int* in_sizes, int n_in,
                              void* d_out, int out_size, void* d_ws, size_t ws_size,
                              hipStream_t stream)
{
    (void)n_in; (void)d_ws; (void)ws_size; (void)out_size;

    // Chebyshev coefficients of log on [a,b] = [0.75, 8.75]:
    // log(m + h t) = log(h/(2g)) + sum_{k>=1} 2(-1)^{k+1} g^k / k * T_k(t)
    // h = 4 (power of two => X/4 exact in f16 from bf16 input), m = 4.75.
    const double a = 0.75, bnd = 8.75;
    const double m = 0.5 * (a + bnd), h = 0.5 * (bnd - a);
    const double alpha = h / m;
    const double gam = (1.0 - sqrt(1.0 - alpha * alpha)) / alpha;

    Coeffs co;
    co.c[0] = (float)log(h / (2.0 * gam));
    double g = 1.0;
    for (int k = 1; k <= NDEG; ++k) {
        g *= gam;
        co.c[k] = (float)((((k & 1) ? 2.0 : -2.0) * g) / (double)k);
    }

    const int B = in_sizes[0] / (NDIM * NDIM);
    spd_log_mfma<<<B, 256, 0, stream>>>(d_in[0], (float*)d_out, co);
}